// Round 1
// baseline (9270.078 us; speedup 1.0000x reference)
//
#include <hip/hip_runtime.h>
#include <math.h>

#define HID 64
#define NEG 0.2f

// order-preserving float<->uint encoding for atomicMax on floats
__device__ __forceinline__ unsigned enc_f(float f) {
    unsigned u = __float_as_uint(f);
    return (u & 0x80000000u) ? ~u : (u | 0x80000000u);
}
__device__ __forceinline__ float dec_f(unsigned u) {
    return __uint_as_float((u & 0x80000000u) ? (u & 0x7fffffffu) : ~u);
}
#define ENC_NEGINF 0x007FFFFFu  // enc(-inf)

// ---------------- node transform: h = x@W, s = h.a_s, d = h.a_d, init m/denom/acc
template <int CIN>
__global__ void transform_k(const float* __restrict__ xin,
                            const float* __restrict__ W,      // [CIN][64]
                            const float* __restrict__ avs,    // [64]
                            const float* __restrict__ avd,    // [64]
                            float* __restrict__ h,            // [n][64]
                            float* __restrict__ s_out, float* __restrict__ d_out,
                            unsigned* __restrict__ menc, float* __restrict__ denom,
                            float* __restrict__ acc, int n) {
    __shared__ float Wl[CIN * HID];
    __shared__ float asl[HID], adl[HID];
    for (int i = threadIdx.x; i < CIN * HID; i += blockDim.x) Wl[i] = W[i];
    if (threadIdx.x < HID) { asl[threadIdx.x] = avs[threadIdx.x]; adl[threadIdx.x] = avd[threadIdx.x]; }
    __syncthreads();
    int lane = threadIdx.x & 63;
    int wid = (blockIdx.x * blockDim.x + threadIdx.x) >> 6;
    int nw = (gridDim.x * blockDim.x) >> 6;
    for (int i = wid; i < n; i += nw) {
        float hv = 0.f;
        if (CIN == 1) {
            hv = xin[i] * Wl[lane];
        } else {
            float xv = xin[i * CIN + lane];  // CIN==64, coalesced
#pragma unroll
            for (int k = 0; k < CIN; ++k)
                hv += __shfl(xv, k) * Wl[k * HID + lane];
        }
        h[i * HID + lane] = hv;
        acc[i * HID + lane] = 0.f;
        float sv = hv * asl[lane], dv = hv * adl[lane];
#pragma unroll
        for (int off = 32; off > 0; off >>= 1) {
            sv += __shfl_xor(sv, off);
            dv += __shfl_xor(dv, off);
        }
        if (lane == 0) {
            s_out[i] = sv; d_out[i] = dv;
            menc[i] = ENC_NEGINF; denom[i] = 0.f;
        }
    }
}

// last layer transform: 64 -> 1
__global__ void transform_last_k(const float* __restrict__ xin,  // [n][64]
                                 const float* __restrict__ WL,   // [64]
                                 const float* __restrict__ asL, const float* __restrict__ adL,
                                 float* __restrict__ hL,         // [n]
                                 float* __restrict__ s_out, float* __restrict__ d_out,
                                 unsigned* __restrict__ menc, float* __restrict__ denom,
                                 float* __restrict__ acc1, int n) {
    __shared__ float Wl[HID];
    if (threadIdx.x < HID) Wl[threadIdx.x] = WL[threadIdx.x];
    __syncthreads();
    float aS = asL[0], aD = adL[0];
    int lane = threadIdx.x & 63;
    int wid = (blockIdx.x * blockDim.x + threadIdx.x) >> 6;
    int nw = (gridDim.x * blockDim.x) >> 6;
    for (int i = wid; i < n; i += nw) {
        float hv = xin[i * HID + lane] * Wl[lane];
#pragma unroll
        for (int off = 32; off > 0; off >>= 1) hv += __shfl_xor(hv, off);
        if (lane == 0) {
            hL[i] = hv;
            s_out[i] = hv * aS; d_out[i] = hv * aD;
            menc[i] = ENC_NEGINF; denom[i] = 0.f; acc1[i] = 0.f;
        }
    }
}

// ---------------- edge pass A: segment max of leaky(s[u]+d[v]) over dst
__global__ void edge_max_k(const int* __restrict__ ei, int E, int n,
                           const float* __restrict__ s, const float* __restrict__ d,
                           unsigned* __restrict__ menc) {
    int tot = E + n;
    for (int e = blockIdx.x * blockDim.x + threadIdx.x; e < tot; e += gridDim.x * blockDim.x) {
        int u, v;
        if (e < E) { u = ei[e]; v = ei[E + e]; } else { u = e - E; v = u; }
        float t = s[u] + d[v];
        t = t > 0.f ? t : NEG * t;
        atomicMax(&menc[v], enc_f(t));
    }
}

// ---------------- edge pass B: ex = exp(e - m), denom += ex, acc[v] += ex*h[u]
__global__ void edge_acc_k(const int* __restrict__ ei, int E, int n,
                           const float* __restrict__ s, const float* __restrict__ d,
                           const unsigned* __restrict__ menc,
                           const float* __restrict__ h,
                           float* __restrict__ denom, float* __restrict__ acc) {
    int lane = threadIdx.x & 63;
    int wid = (blockIdx.x * blockDim.x + threadIdx.x) >> 6;
    int nw = (gridDim.x * blockDim.x) >> 6;
    int tot = E + n;
    for (int e = wid; e < tot; e += nw) {
        int u, v;
        if (e < E) { u = ei[e]; v = ei[E + e]; } else { u = e - E; v = u; }
        float t = s[u] + d[v];
        t = t > 0.f ? t : NEG * t;
        float ex = __expf(t - dec_f(menc[v]));
        if (lane == 0) atomicAdd(&denom[v], ex);
        atomicAdd(&acc[v * HID + lane], ex * h[u * HID + lane]);
    }
}

// last layer edge acc (1 channel), thread-per-edge
__global__ void edge_acc1_k(const int* __restrict__ ei, int E, int n,
                            const float* __restrict__ s, const float* __restrict__ d,
                            const unsigned* __restrict__ menc,
                            const float* __restrict__ hL,
                            float* __restrict__ denom, float* __restrict__ acc1) {
    int tot = E + n;
    for (int e = blockIdx.x * blockDim.x + threadIdx.x; e < tot; e += gridDim.x * blockDim.x) {
        int u, v;
        if (e < E) { u = ei[e]; v = ei[E + e]; } else { u = e - E; v = u; }
        float t = s[u] + d[v];
        t = t > 0.f ? t : NEG * t;
        float ex = __expf(t - dec_f(menc[v]));
        atomicAdd(&denom[v], ex);
        atomicAdd(&acc1[v], ex * hL[u]);
    }
}

// ---------------- finalize: act(acc/denom + b)
__global__ void finalize_k(const float* __restrict__ acc, const float* __restrict__ denom,
                           const float* __restrict__ b, float* __restrict__ xout, int n) {
    int tot = n * HID;
    for (int idx = blockIdx.x * blockDim.x + threadIdx.x; idx < tot; idx += gridDim.x * blockDim.x) {
        int i = idx >> 6, c = idx & 63;
        float v = acc[idx] / denom[i] + b[c];
        xout[idx] = v > 0.f ? v : 0.f;  // ReLU
    }
}

__global__ void finalize_last_k(const float* __restrict__ acc1, const float* __restrict__ denom,
                                const float* __restrict__ bL, float* __restrict__ out, int n) {
    float bias = bL[0];
    for (int i = blockIdx.x * blockDim.x + threadIdx.x; i < n; i += gridDim.x * blockDim.x) {
        float v = acc1[i] / denom[i] + bias;
        out[i] = 1.f / (1.f + __expf(-v));  // sigmoid
    }
}

extern "C" void kernel_launch(void* const* d_in, const int* in_sizes, int n_in,
                              void* d_out, int out_size, void* d_ws, size_t ws_size,
                              hipStream_t stream) {
    const float* x   = (const float*)d_in[0];
    const int*   ei  = (const int*)d_in[1];
    // d_in[2] = edge_weight: ignored (edge_dim=None in reference)
    const float* W0  = (const float*)d_in[3];
    const float* as0 = (const float*)d_in[4];
    const float* ad0 = (const float*)d_in[5];
    const float* b0  = (const float*)d_in[6];
    const float* Wm  = (const float*)d_in[7];
    const float* asm_ = (const float*)d_in[8];
    const float* adm = (const float*)d_in[9];
    const float* bm  = (const float*)d_in[10];
    const float* WL  = (const float*)d_in[11];
    const float* asL = (const float*)d_in[12];
    const float* adL = (const float*)d_in[13];
    const float* bL  = (const float*)d_in[14];

    const int n = in_sizes[0];      // 100000 (x is [N,1])
    const int E = in_sizes[1] / 2;  // 6400000

    // workspace layout (floats): h[n*64] | xa[n*64] | xb[n*64] | s[n] | d[n] | menc[n] | denom[n]
    float* ws    = (float*)d_ws;
    float* h     = ws;
    float* xa    = ws + (size_t)n * HID;
    float* xb    = ws + 2 * (size_t)n * HID;
    float* sbuf  = ws + 3 * (size_t)n * HID;
    float* dbuf  = sbuf + n;
    unsigned* menc = (unsigned*)(dbuf + n);
    float* denom = dbuf + 2 * n;

    const int BLK = 256;
    const int gTrans = 2048;   // 8192 waves
    const int gEdgeT = 4096;   // thread-per-edge kernels
    const int gEdgeW = 8192;   // wave-per-edge kernels (32768 waves)
    const int gNode  = 4096;

    // ---- layer 0: 1 -> 64, ReLU
    transform_k<1><<<gTrans, BLK, 0, stream>>>(x, W0, as0, ad0, h, sbuf, dbuf, menc, denom, xa, n);
    edge_max_k<<<gEdgeT, BLK, 0, stream>>>(ei, E, n, sbuf, dbuf, menc);
    edge_acc_k<<<gEdgeW, BLK, 0, stream>>>(ei, E, n, sbuf, dbuf, menc, h, denom, xa);
    finalize_k<<<gNode, BLK, 0, stream>>>(xa, denom, b0, xa, n);

    float* cur = xa;
    float* oth = xb;
    // ---- middle layers: 64 -> 64, ReLU
    for (int l = 0; l < 3; ++l) {
        transform_k<64><<<gTrans, BLK, 0, stream>>>(cur, Wm + (size_t)l * HID * HID,
                                                    asm_ + l * HID, adm + l * HID,
                                                    h, sbuf, dbuf, menc, denom, oth, n);
        edge_max_k<<<gEdgeT, BLK, 0, stream>>>(ei, E, n, sbuf, dbuf, menc);
        edge_acc_k<<<gEdgeW, BLK, 0, stream>>>(ei, E, n, sbuf, dbuf, menc, h, denom, oth);
        finalize_k<<<gNode, BLK, 0, stream>>>(oth, denom, bm + l * HID, oth, n);
        float* t = cur; cur = oth; oth = t;
    }

    // ---- last layer: 64 -> 1, sigmoid. hL reuses h[0..n), acc1 reuses oth[0..n)
    transform_last_k<<<gTrans, BLK, 0, stream>>>(cur, WL, asL, adL, h, sbuf, dbuf, menc, denom, oth, n);
    edge_max_k<<<gEdgeT, BLK, 0, stream>>>(ei, E, n, sbuf, dbuf, menc);
    edge_acc1_k<<<gEdgeT, BLK, 0, stream>>>(ei, E, n, sbuf, dbuf, menc, h, denom, oth);
    finalize_last_k<<<512, BLK, 0, stream>>>(oth, denom, bL, (float*)d_out, n);
}

// Round 2
// 2379.318 us; speedup vs baseline: 3.8961x; 3.8961x over previous
//
#include <hip/hip_runtime.h>
#include <math.h>

#define HID 64
#define NEG 0.2f
#define CAP 192   // per-wave LDS stash of edge logits; Poisson(64) max-deg over 1e5 nodes ~<120

// ---------------- node transform: h = x@W, s = h.a_s, d = h.a_d
template <int CIN>
__global__ void transform_k(const float* __restrict__ xin,
                            const float* __restrict__ W,      // [CIN][64]
                            const float* __restrict__ avs,    // [64]
                            const float* __restrict__ avd,    // [64]
                            float* __restrict__ h,            // [n][64]
                            float* __restrict__ s_out, float* __restrict__ d_out,
                            int n) {
    __shared__ float Wl[CIN * HID];
    __shared__ float asl[HID], adl[HID];
    for (int i = threadIdx.x; i < CIN * HID; i += blockDim.x) Wl[i] = W[i];
    if (threadIdx.x < HID) { asl[threadIdx.x] = avs[threadIdx.x]; adl[threadIdx.x] = avd[threadIdx.x]; }
    __syncthreads();
    int lane = threadIdx.x & 63;
    int wid = (blockIdx.x * blockDim.x + threadIdx.x) >> 6;
    int nw = (gridDim.x * blockDim.x) >> 6;
    for (int i = wid; i < n; i += nw) {
        float hv = 0.f;
        if (CIN == 1) {
            hv = xin[i] * Wl[lane];
        } else {
            float xv = xin[(size_t)i * CIN + lane];  // CIN==64, coalesced
#pragma unroll
            for (int k = 0; k < CIN; ++k)
                hv += __shfl(xv, k) * Wl[k * HID + lane];
        }
        h[(size_t)i * HID + lane] = hv;
        float sv = hv * asl[lane], dv = hv * adl[lane];
#pragma unroll
        for (int off = 32; off > 0; off >>= 1) {
            sv += __shfl_xor(sv, off);
            dv += __shfl_xor(dv, off);
        }
        if (lane == 0) { s_out[i] = sv; d_out[i] = dv; }
    }
}

// last layer transform: 64 -> 1
__global__ void transform_last_k(const float* __restrict__ xin,  // [n][64]
                                 const float* __restrict__ WL,   // [64]
                                 const float* __restrict__ asL, const float* __restrict__ adL,
                                 float* __restrict__ hL,         // [n]
                                 float* __restrict__ s_out, float* __restrict__ d_out,
                                 int n) {
    __shared__ float Wl[HID];
    if (threadIdx.x < HID) Wl[threadIdx.x] = WL[threadIdx.x];
    __syncthreads();
    float aS = asL[0], aD = adL[0];
    int lane = threadIdx.x & 63;
    int wid = (blockIdx.x * blockDim.x + threadIdx.x) >> 6;
    int nw = (gridDim.x * blockDim.x) >> 6;
    for (int i = wid; i < n; i += nw) {
        float hv = xin[(size_t)i * HID + lane] * Wl[lane];
#pragma unroll
        for (int off = 32; off > 0; off >>= 1) hv += __shfl_xor(hv, off);
        if (lane == 0) {
            hL[i] = hv;
            s_out[i] = hv * aS; d_out[i] = hv * aD;
        }
    }
}

// ---------------- CSR build (per call; ws is re-poisoned) ----------------
__global__ void init_deg_k(int* __restrict__ deg, int n) {
    int i = blockIdx.x * blockDim.x + threadIdx.x;
    if (i < n) deg[i] = 1;  // self loop
}

__global__ void hist_k(const int* __restrict__ ei, int E, int* __restrict__ deg) {
    for (int e = blockIdx.x * blockDim.x + threadIdx.x; e < E; e += gridDim.x * blockDim.x)
        atomicAdd(&deg[ei[E + e]], 1);
}

// single-block exclusive scan of deg[0..n) -> off[0..n], cursor copy
__global__ void scan_k(const int* __restrict__ deg, int* __restrict__ off,
                       int* __restrict__ cursor, int n) {
    __shared__ int sums[1024];
    int t = threadIdx.x;
    int per = (n + 1023) / 1024;
    int beg = t * per;
    int end = beg + per; if (end > n) end = n;
    int s = 0;
    for (int i = beg; i < end && i >= 0; ++i) s += deg[i];
    sums[t] = s;
    __syncthreads();
    for (int o = 1; o < 1024; o <<= 1) {
        int v = (t >= o) ? sums[t - o] : 0;
        __syncthreads();
        sums[t] += v;
        __syncthreads();
    }
    int run = (t == 0) ? 0 : sums[t - 1];
    for (int i = beg; i < end && i >= 0; ++i) {
        int dg = deg[i];
        off[i] = run; cursor[i] = run;
        run += dg;
    }
    if (t == 1023) off[n] = run;
}

__global__ void scatter_k(const int* __restrict__ ei, int E, int n,
                          int* __restrict__ cursor, int* __restrict__ csr) {
    int tot = E + n;
    for (int e = blockIdx.x * blockDim.x + threadIdx.x; e < tot; e += gridDim.x * blockDim.x) {
        int u, v;
        if (e < E) { u = ei[e]; v = ei[E + e]; } else { u = e - E; v = u; }
        int pos = atomicAdd(&cursor[v], 1);
        csr[pos] = u;
    }
}

// ---------------- fused per-node softmax + aggregate (wave per node, no atomics)
__global__ __launch_bounds__(256) void gat_agg_k(
    const int* __restrict__ off, const int* __restrict__ csr,
    const float* __restrict__ s, const float* __restrict__ d,
    const float* __restrict__ h, const float* __restrict__ b,
    float* __restrict__ out, int n) {
    __shared__ float tbuf[4][CAP];
    __shared__ int   ubuf[4][CAP];
    int lane = threadIdx.x & 63;
    int wsub = threadIdx.x >> 6;
    int wid = (blockIdx.x * blockDim.x + threadIdx.x) >> 6;
    int nw = (gridDim.x * blockDim.x) >> 6;
    float bias = b[lane];
    for (int v = wid; v < n; v += nw) {
        int beg = off[v];
        int deg = off[v + 1] - beg;
        float dv = d[v];
        // phase A: logits (lanes strided over edges), stash t,u in LDS, wave max
        float m = -INFINITY;
        for (int idx = lane; idx < deg; idx += 64) {
            int u = csr[beg + idx];
            float t = s[u] + dv;
            t = t > 0.f ? t : NEG * t;
            if (idx < CAP) { ubuf[wsub][idx] = u; tbuf[wsub][idx] = t; }
            m = fmaxf(m, t);
        }
#pragma unroll
        for (int o = 32; o > 0; o >>= 1) m = fmaxf(m, __shfl_xor(m, o));
        // phase B: exp + denom (exp issued once per edge, not per edge*64)
        float l = 0.f;
        for (int idx = lane; idx < deg; idx += 64) {
            float t;
            if (idx < CAP) t = tbuf[wsub][idx];
            else { int u = csr[beg + idx]; t = s[u] + dv; t = t > 0.f ? t : NEG * t; }
            float ex = __expf(t - m);
            l += ex;
            if (idx < CAP) tbuf[wsub][idx] = ex;
        }
#pragma unroll
        for (int o = 32; o > 0; o >>= 1) l += __shfl_xor(l, o);
        // phase C: register accumulate, 256B coalesced gather of h[u]
        float acc = 0.f;
        int cnt = deg < CAP ? deg : CAP;
#pragma unroll 4
        for (int j = 0; j < cnt; ++j) {
            float ex = tbuf[wsub][j];     // broadcast LDS read
            int u = ubuf[wsub][j];        // broadcast LDS read
            acc += ex * h[(size_t)u * HID + lane];
        }
        for (int j = CAP; j < deg; ++j) {  // cold fallback, deg>CAP never expected
            int u = csr[beg + j];
            float t = s[u] + dv; t = t > 0.f ? t : NEG * t;
            acc += __expf(t - m) * h[(size_t)u * HID + lane];
        }
        float r = acc / l + bias;
        out[(size_t)v * HID + lane] = r > 0.f ? r : 0.f;  // ReLU
    }
}

// last layer aggregate (1 channel): lanes strided over edges, full wave reduce
__global__ void gat_agg1_k(const int* __restrict__ off, const int* __restrict__ csr,
                           const float* __restrict__ s, const float* __restrict__ d,
                           const float* __restrict__ hL, const float* __restrict__ bL,
                           float* __restrict__ out, int n) {
    int lane = threadIdx.x & 63;
    int wid = (blockIdx.x * blockDim.x + threadIdx.x) >> 6;
    int nw = (gridDim.x * blockDim.x) >> 6;
    float bias = bL[0];
    for (int v = wid; v < n; v += nw) {
        int beg = off[v], end = off[v + 1];
        float dv = d[v];
        float m = -INFINITY;
        for (int idx = beg + lane; idx < end; idx += 64) {
            int u = csr[idx];
            float t = s[u] + dv;
            t = t > 0.f ? t : NEG * t;
            m = fmaxf(m, t);
        }
#pragma unroll
        for (int o = 32; o > 0; o >>= 1) m = fmaxf(m, __shfl_xor(m, o));
        float l = 0.f, acc = 0.f;
        for (int idx = beg + lane; idx < end; idx += 64) {
            int u = csr[idx];
            float t = s[u] + dv;
            t = t > 0.f ? t : NEG * t;
            float ex = __expf(t - m);
            l += ex;
            acc += ex * hL[u];
        }
#pragma unroll
        for (int o = 32; o > 0; o >>= 1) {
            l += __shfl_xor(l, o);
            acc += __shfl_xor(acc, o);
        }
        if (lane == 0) {
            float r = acc / l + bias;
            out[v] = 1.f / (1.f + __expf(-r));  // sigmoid
        }
    }
}

extern "C" void kernel_launch(void* const* d_in, const int* in_sizes, int n_in,
                              void* d_out, int out_size, void* d_ws, size_t ws_size,
                              hipStream_t stream) {
    const float* x   = (const float*)d_in[0];
    const int*   ei  = (const int*)d_in[1];
    // d_in[2] = edge_weight: ignored (edge_dim=None in reference)
    const float* W0  = (const float*)d_in[3];
    const float* as0 = (const float*)d_in[4];
    const float* ad0 = (const float*)d_in[5];
    const float* b0  = (const float*)d_in[6];
    const float* Wm  = (const float*)d_in[7];
    const float* asm_ = (const float*)d_in[8];
    const float* adm = (const float*)d_in[9];
    const float* bm  = (const float*)d_in[10];
    const float* WL  = (const float*)d_in[11];
    const float* asL = (const float*)d_in[12];
    const float* adL = (const float*)d_in[13];
    const float* bL  = (const float*)d_in[14];

    const int n = in_sizes[0];      // 100000
    const int E = in_sizes[1] / 2;  // 6400000

    // workspace: h[n*64] | A[n*64] | s[n] | d[n] | deg[n] | off[n+1] | cursor[n] | csr[E+n]
    float* ws   = (float*)d_ws;
    float* h    = ws;
    float* A    = ws + (size_t)n * HID;
    float* sbuf = ws + 2 * (size_t)n * HID;
    float* dbuf = sbuf + n;
    int* deg    = (int*)(dbuf + n);
    int* off    = deg + n;
    int* cursor = off + n + 1;
    int* csr    = cursor + n;

    const int BLK = 256;
    const int gTrans = 2048;
    const int gEdge  = 4096;
    const int gAgg   = (n + 3) / 4;   // 4 waves/block -> 1 node/wave

    // ---- CSR build (dst-sorted adjacency, self-loops included)
    init_deg_k<<<(n + BLK - 1) / BLK, BLK, 0, stream>>>(deg, n);
    hist_k<<<gEdge, BLK, 0, stream>>>(ei, E, deg);
    scan_k<<<1, 1024, 0, stream>>>(deg, off, cursor, n);
    scatter_k<<<gEdge, BLK, 0, stream>>>(ei, E, n, cursor, csr);

    // ---- layer 0: 1 -> 64, ReLU
    transform_k<1><<<gTrans, BLK, 0, stream>>>(x, W0, as0, ad0, h, sbuf, dbuf, n);
    gat_agg_k<<<gAgg, BLK, 0, stream>>>(off, csr, sbuf, dbuf, h, b0, A, n);

    // ---- middle layers: 64 -> 64, ReLU
    for (int l = 0; l < 3; ++l) {
        transform_k<64><<<gTrans, BLK, 0, stream>>>(A, Wm + (size_t)l * HID * HID,
                                                    asm_ + l * HID, adm + l * HID,
                                                    h, sbuf, dbuf, n);
        gat_agg_k<<<gAgg, BLK, 0, stream>>>(off, csr, sbuf, dbuf, h, bm + l * HID, A, n);
    }

    // ---- last layer: 64 -> 1, sigmoid
    transform_last_k<<<gTrans, BLK, 0, stream>>>(A, WL, asL, adL, h, sbuf, dbuf, n);
    gat_agg1_k<<<gEdge, BLK, 0, stream>>>(off, csr, sbuf, dbuf, h, bL, (float*)d_out, n);
}